// Round 6
// baseline (426.157 us; speedup 1.0000x reference)
//
#include <hip/hip_runtime.h>
#include <hip/hip_bf16.h>
#include <math.h>

constexpr int DXc = 1024;
constexpr int DZc = 1024;
constexpr int LXc = 4096;
constexpr int LZc = 4096;
constexpr int DAc = 1024;   // DATTN
constexpr int DOc = 1024;   // DOUT

typedef __attribute__((ext_vector_type(8))) short bf16x8;   // 8 bf16 = 4 VGPRs
typedef __attribute__((ext_vector_type(4))) float f32x4;

__device__ __forceinline__ ushort f2bf(float f) {
    __hip_bfloat16 h = __float2bfloat16(f);
    return *reinterpret_cast<ushort*>(&h);
}
__device__ __forceinline__ float bflo(unsigned u) {
    return __builtin_bit_cast(float, u << 16);
}
__device__ __forceinline__ float bfhi(unsigned u) {
    return __builtin_bit_cast(float, u & 0xffff0000u);
}

enum BiasMode { BIAS_NONE, BIAS_M, BIAS_N };

#define SCHED0() __builtin_amdgcn_sched_barrier(0)
#define BAR2()   do { SCHED0(); __builtin_amdgcn_s_barrier(); SCHED0(); } while (0)
#define LGKM0()  do { asm volatile("s_waitcnt lgkmcnt(0)" ::: "memory"); SCHED0(); } while (0)
#define VMCNT(n) do { asm volatile("s_waitcnt vmcnt(" #n ")" ::: "memory"); SCHED0(); } while (0)

// ---------------------------------------------------------------------------
// Grid-wide barrier for a fully-co-resident grid (256 blocks x 1/CU).
// Release: __syncthreads drains each wave's stores to L2 (compiler emits
// vmcnt(0) before s_barrier), then an agent-scope release fence writes the
// XCD L2 back to the coherence point. Acquire: after the spin, an agent-scope
// acquire fence invalidates stale L1/L2 lines — the same semantics a kernel
// boundary provides (per-XCD L2s are not cross-coherent otherwise).
// Monotonic counter: phase p waits for count >= p*256; prep re-zeroes it.
// ---------------------------------------------------------------------------
__device__ __forceinline__ void gridbar(unsigned* cnt, unsigned target) {
    __syncthreads();
    if (threadIdx.x == 0) {
        __builtin_amdgcn_fence(__ATOMIC_RELEASE, "agent");
        __hip_atomic_fetch_add(cnt, 1u, __ATOMIC_RELAXED, __HIP_MEMORY_SCOPE_AGENT);
        while (__hip_atomic_load(cnt, __ATOMIC_RELAXED, __HIP_MEMORY_SCOPE_AGENT) < target)
            __builtin_amdgcn_s_sleep(8);
    }
    __syncthreads();
    __builtin_amdgcn_fence(__ATOMIC_ACQUIRE, "agent");
}

// ---------------------------------------------------------------------------
// 256x256 tile, BK=64, 8 waves (2M x 4N), 8-phase counted-vmcnt schedule
// (T2 swizzle + T3/T4 + T5).  C[m,n] = sum_k A[m,k]*B[n,k], A,B K-major bf16.
// Main loop + epilogues = round-1 PROVEN version (plain bf16-out / fp32-split).
// ---------------------------------------------------------------------------
template<BiasMode BMODE, bool OUT_BF16, bool SPLIT>
__device__ __forceinline__ void gemm256(
    const ushort* __restrict__ A, const ushort* __restrict__ B,
    const float* __restrict__ bias, void* __restrict__ Cv,
    int M, int N, int K, int lda, int ldb, int ldc,
    int m0, int n0, int kbase, int zsplit, char* smem)
{
    const int tid  = threadIdx.x;
    const int wid  = tid >> 6, lane = tid & 63;
    const int wr   = wid >> 2, wc = wid & 3;          // 2M x 4N waves
    const int lrow = lane & 15, quad = lane >> 4;
    const int swz  = (lrow & 7) << 4;
    const int cx0  = (quad * 16) ^ swz;               // byte col, kstep 0
    const int cx1  = (64 + quad * 16) ^ swz;          // byte col, kstep 1
    const int raB  = (wr * 16 + lrow) * 128;          // A per-lane row base (bytes)
    const int rbB  = (wc * 16 + lrow) * 128;          // B per-lane row base (bytes)

    char* const Ab0 = smem;                 // A buf0: 32 KB ([256][64] bf16)
    char* const Ab1 = smem + 32768;         // A buf1
    char* const Bb0 = smem + 65536;         // B buf0
    char* const Bb1 = smem + 98304;         // B buf1

    auto stage = [&](const ushort* __restrict__ Mat, int ld, int r0, int kc,
                     char* dstBuf, int h) {
        #pragma unroll
        for (int r = 0; r < 2; ++r) {
            const int q = h * 16384 + r * 8192 + wid * 1024 + lane * 16; // phys LDS byte
            const int p = q ^ (((q >> 7) & 7) << 4);                    // logical byte
            const ushort* g = Mat + (size_t)(r0 + (p >> 7)) * ld + kc + ((p & 127) >> 1);
            __builtin_amdgcn_global_load_lds(
                (const __attribute__((address_space(1))) void*)g,
                (__attribute__((address_space(3))) void*)(dstBuf + h * 16384 + r * 8192 + wid * 1024),
                16, 0, 0);
        }
    };

    f32x4  acc[8][4] = {};
    bf16x8 alo[4][2], ahi[4][2], blo[2][2], bhi[2][2];

    auto ldLo = [&](char* Abuf, char* Bbuf) {       // 12 ds_read_b128
        #pragma unroll
        for (int m = 0; m < 4; ++m) {
            alo[m][0] = *reinterpret_cast<const bf16x8*>(Abuf + m * 4096 + raB + cx0);
            alo[m][1] = *reinterpret_cast<const bf16x8*>(Abuf + m * 4096 + raB + cx1);
        }
        #pragma unroll
        for (int n = 0; n < 2; ++n) {
            blo[n][0] = *reinterpret_cast<const bf16x8*>(Bbuf + n * 8192 + rbB + cx0);
            blo[n][1] = *reinterpret_cast<const bf16x8*>(Bbuf + n * 8192 + rbB + cx1);
        }
    };
    auto ldAhi = [&](char* Abuf) {                  // 8 ds_read_b128
        #pragma unroll
        for (int m = 0; m < 4; ++m) {
            ahi[m][0] = *reinterpret_cast<const bf16x8*>(Abuf + (m + 4) * 4096 + raB + cx0);
            ahi[m][1] = *reinterpret_cast<const bf16x8*>(Abuf + (m + 4) * 4096 + raB + cx1);
        }
    };
    auto ldBhi = [&](char* Bbuf) {                  // 4 ds_read_b128
        #pragma unroll
        for (int n = 0; n < 2; ++n) {
            bhi[n][0] = *reinterpret_cast<const bf16x8*>(Bbuf + (n + 2) * 8192 + rbB + cx0);
            bhi[n][1] = *reinterpret_cast<const bf16x8*>(Bbuf + (n + 2) * 8192 + rbB + cx1);
        }
    };
    auto mmaQ = [&](bf16x8 (&a)[4][2], bf16x8 (&b)[2][2], int mh, int nh) {  // 16 MFMA
        __builtin_amdgcn_s_setprio(1);
        #pragma unroll
        for (int m = 0; m < 4; ++m)
            #pragma unroll
            for (int n = 0; n < 2; ++n) {
                f32x4& c = acc[mh * 4 + m][nh * 2 + n];
                c = __builtin_amdgcn_mfma_f32_16x16x32_bf16(a[m][0], b[n][0], c, 0, 0, 0);
                c = __builtin_amdgcn_mfma_f32_16x16x32_bf16(a[m][1], b[n][1], c, 0, 0, 0);
            }
        __builtin_amdgcn_s_setprio(0);
    };

    const int NIT = K >> 7;   // iterations; 2 K-tiles (BK=64) each

    stage(A, lda, m0, kbase,      Ab0, 0);
    stage(B, ldb, n0, kbase,      Bb0, 0);
    stage(B, ldb, n0, kbase,      Bb0, 1);
    stage(A, lda, m0, kbase,      Ab0, 1);
    VMCNT(4);
    stage(A, lda, m0, kbase + 64, Ab1, 0);
    stage(B, ldb, n0, kbase + 64, Bb1, 0);
    stage(B, ldb, n0, kbase + 64, Bb1, 1);
    VMCNT(6);
    BAR2();

    #pragma unroll 1
    for (int it = 0; it < NIT; ++it) {
        const bool st  = (it < NIT - 1);
        const int kU   = kbase + (2 * it + 1) * 64;
        const int kT2  = kbase + (2 * it + 2) * 64;
        const int kT3  = kbase + (2 * it + 3) * 64;

        ldLo(Ab0, Bb0);
        stage(A, lda, m0, kU, Ab1, 1);
        asm volatile("s_waitcnt lgkmcnt(8)" ::: "memory");
        BAR2(); LGKM0();
        mmaQ(alo, blo, 0, 0);
        BAR2();
        ldBhi(Bb0);
        if (st) stage(A, lda, m0, kT2, Ab0, 0);
        BAR2(); LGKM0();
        mmaQ(alo, bhi, 0, 1);
        BAR2();
        ldAhi(Ab0);
        if (st) stage(B, ldb, n0, kT2, Bb0, 0);
        BAR2(); LGKM0();
        mmaQ(ahi, bhi, 1, 1);
        BAR2();
        if (st) { stage(B, ldb, n0, kT2, Bb0, 1); VMCNT(6); }
        else    { VMCNT(0); }
        BAR2();
        mmaQ(ahi, blo, 1, 0);
        BAR2();
        ldLo(Ab1, Bb1);
        if (st) stage(A, lda, m0, kT2, Ab0, 1);
        asm volatile("s_waitcnt lgkmcnt(8)" ::: "memory");
        BAR2(); LGKM0();
        mmaQ(alo, blo, 0, 0);
        BAR2();
        ldBhi(Bb1);
        if (st) stage(A, lda, m0, kT3, Ab1, 0);
        BAR2(); LGKM0();
        mmaQ(alo, bhi, 0, 1);
        BAR2();
        ldAhi(Ab1);
        if (st) stage(B, ldb, n0, kT3, Bb1, 0);
        BAR2(); LGKM0();
        mmaQ(ahi, bhi, 1, 1);
        BAR2();
        if (st) { stage(B, ldb, n0, kT3, Bb1, 1); VMCNT(6); }
        else    { VMCNT(0); }
        BAR2();
        mmaQ(ahi, blo, 1, 0);
        BAR2();
    }

    float*  Cf = (float*)Cv + (SPLIT ? (size_t)zsplit * (size_t)M * ldc : 0);
    ushort* Cb = (ushort*)Cv;
    #pragma unroll
    for (int m = 0; m < 8; ++m) {
        const int rowb = m0 + 32 * m + wr * 16 + quad * 4;
        #pragma unroll
        for (int r = 0; r < 4; ++r) {
            const int row = rowb + r;
            const float bm = (BMODE == BIAS_M) ? bias[row] : 0.0f;
            #pragma unroll
            for (int n = 0; n < 4; ++n) {
                const int col = n0 + 64 * n + wc * 16 + lrow;
                float v = acc[m][n][r] + ((BMODE == BIAS_N) ? bias[col] : bm);
                if (OUT_BF16) Cb[(size_t)row * ldc + col] = f2bf(v);
                else          Cf[(size_t)row * ldc + col] = v;
            }
        }
    }
}

// ---------------------------------------------------------------------------
// Fused attention: proj -> score -> softmax -> out(split-K) -> reduce,
// one dispatch, 256 blocks x 512 thr (1 block/CU, co-resident), grid barriers.
// ---------------------------------------------------------------------------
__global__ __launch_bounds__(512, 2)
void fused_kernel(const ushort* __restrict__ XT, const ushort* __restrict__ ZT,
                  const ushort* __restrict__ Wqb, const ushort* __restrict__ Wkb,
                  const ushort* __restrict__ Wvb,
                  const float* __restrict__ bq, const float* __restrict__ bk,
                  const float* __restrict__ bv,
                  ushort* __restrict__ qT, ushort* __restrict__ kT,
                  ushort* __restrict__ vB, ushort* __restrict__ sTb,
                  const unsigned* __restrict__ bits, float* __restrict__ P,
                  unsigned* __restrict__ barcnt, float* __restrict__ out)
{
    extern __shared__ char smem[];
    const int b = blockIdx.x;

    // ---- phase 1: projections (192 of 256 blocks active)
    if (b < 64) {
        gemm256<BIAS_N, true, false>(XT, Wqb, bq, qT, LXc, DAc, DXc, DXc, DXc, DAc,
                                     (b >> 2) * 256, (b & 3) * 256, 0, 0, smem);
    } else if (b < 128) {
        const int c = b - 64;
        gemm256<BIAS_N, true, false>(ZT, Wkb, bk, kT, LZc, DAc, DZc, DZc, DZc, DAc,
                                     (c >> 2) * 256, (c & 3) * 256, 0, 0, smem);
    } else if (b < 192) {
        const int c = b - 128;
        gemm256<BIAS_M, true, false>(Wvb, ZT, bv, vB, DOc, LZc, DZc, DZc, DZc, LZc,
                                     (c >> 4) * 256, (c & 15) * 256, 0, 0, smem);
    }
    gridbar(barcnt, 256);

    // ---- phase 2: score  sTb[x,z] = sum_d qT[x,d] kT[z,d]
    gemm256<BIAS_NONE, true, false>(qT, kT, nullptr, sTb, LXc, LZc, DAc, DAc, DAc, LZc,
                                    (b >> 4) * 256, (b & 15) * 256, 0, 0, smem);
    gridbar(barcnt, 512);

    // ---- phase 3: softmax, in place, 2 rows per wave, max-free
    {
        const int lane = threadIdx.x & 63;
        const int wid  = threadIdx.x >> 6;
        constexpr float scale = 1.0f / 32.0f;   // 1/sqrt(1024)
        constexpr float MASKV = -1000.0f / 32.0f;
        #pragma unroll 1
        for (int i = 0; i < 2; ++i) {
            const int x = (b * 8 + wid) * 2 + i;
            ushort* row = sTb + (size_t)x * LZc;
            float v[64];
            float sum = 0.0f;
            #pragma unroll
            for (int c = 0; c < 8; ++c) {
                const uint4 pk = *reinterpret_cast<const uint4*>(row + (size_t)(c * 512 + lane * 8));
                const unsigned* wp = reinterpret_cast<const unsigned*>(&pk);
                const unsigned mb = (bits[(size_t)x * 128 + c * 16 + (lane >> 2)] >> ((lane & 3) * 8)) & 0xffu;
                #pragma unroll
                for (int j = 0; j < 4; ++j) {
                    const float lo = ((mb >> (2 * j))     & 1u) ? bflo(wp[j]) * scale : MASKV;
                    const float hi = ((mb >> (2 * j + 1)) & 1u) ? bfhi(wp[j]) * scale : MASKV;
                    const float el = __expf(lo), eh = __expf(hi);
                    v[c * 8 + 2 * j]     = el;
                    v[c * 8 + 2 * j + 1] = eh;
                    sum += el + eh;
                }
            }
            #pragma unroll
            for (int off = 32; off > 0; off >>= 1)
                sum += __shfl_xor(sum, off, 64);
            const float inv = 1.0f / sum;
            #pragma unroll
            for (int c = 0; c < 8; ++c) {
                uint4 pk;
                unsigned* wp = reinterpret_cast<unsigned*>(&pk);
                #pragma unroll
                for (int j = 0; j < 4; ++j) {
                    const unsigned lo = f2bf(v[c * 8 + 2 * j] * inv);
                    const unsigned hi = f2bf(v[c * 8 + 2 * j + 1] * inv);
                    wp[j] = lo | (hi << 16);
                }
                *reinterpret_cast<uint4*>(row + (size_t)(c * 512 + lane * 8)) = pk;
            }
        }
    }
    gridbar(barcnt, 768);

    // ---- phase 4: out split-K=4 -> fp32 partials P (overlays XT..bits)
    gemm256<BIAS_NONE, false, true>(vB, sTb, nullptr, P, DOc, LXc, LZc / 4,
                                    LZc, LZc, LXc,
                                    ((b >> 4) & 3) * 256, (b & 15) * 256,
                                    (b >> 6) * (LZc / 4), b >> 6, smem);
    gridbar(barcnt, 1024);

    // ---- phase 5: reduce P -> out (grid-stride, 8 float4/thread)
    {
        constexpr size_t total = (size_t)DOc * LXc;
        const int tid = threadIdx.x;
        #pragma unroll
        for (int it = 0; it < 8; ++it) {
            const size_t i = (((size_t)it * 256 + b) * 512 + tid) * 4;
            float4 s = *reinterpret_cast<const float4*>(P + i);
            #pragma unroll
            for (int p = 1; p < 4; ++p) {
                const float4 t = *reinterpret_cast<const float4*>(P + (size_t)p * total + i);
                s.x += t.x; s.y += t.y; s.z += t.z; s.w += t.w;
            }
            *reinterpret_cast<float4*>(out + i) = s;
        }
    }
}

// ---------------------------------------------------------------------------
// Prep (13313 blocks) — round-1 measured-best segments (frozen): X->XT bf16
// LDS transpose, Z->ZT, Wq/Wk/Wv fp32->bf16, mask pack. Final block zeroes
// the grid-barrier counter.
// ---------------------------------------------------------------------------
__global__ __launch_bounds__(256)
void prep_kernel(const float* __restrict__ X, const float* __restrict__ Z,
                 const float* __restrict__ Wq, const float* __restrict__ Wk,
                 const float* __restrict__ Wv, const int* __restrict__ mask,
                 ushort* __restrict__ XT, ushort* __restrict__ ZT,
                 ushort* __restrict__ Wqb, ushort* __restrict__ Wkb,
                 ushort* __restrict__ Wvb, unsigned* __restrict__ bits,
                 unsigned* __restrict__ barcnt)
{
    __shared__ float tile[32][33];
    const int tid = threadIdx.x;
    int b = blockIdx.x;

    if (b < 8192) {   // two transposes, 4096 blocks each: (R=1024, C=4096)
        const float* in  = (b < 4096) ? X : Z;
        ushort*      out = (b < 4096) ? XT : ZT;
        const int local = b & 4095;
        const int bx = local & 127, by = local >> 7;
        const int c0 = bx * 32, r0 = by * 32;
        const int tx = tid & 31, ty = tid >> 5;          // 32 x 8
        #pragma unroll
        for (int i = 0; i < 32; i += 8)
            tile[ty + i][tx] = in[(size_t)(r0 + ty + i) * LXc + c0 + tx];
        __syncthreads();
        #pragma unroll
        for (int i = 0; i < 32; i += 8)
            out[(size_t)(c0 + ty + i) * DXc + r0 + tx] = f2bf(tile[tx][ty + i]);
        return;
    }
    if (b < 11264) {  // three weight converts, 1024 blocks each (1M elems)
        b -= 8192;
        const float* in  = (b < 1024) ? Wq : (b < 2048) ? Wk : Wv;
        ushort*      out = (b < 1024) ? Wqb : (b < 2048) ? Wkb : Wvb;
        const int local = b & 1023;
        const size_t i = ((size_t)local * 256 + tid) * 4;
        float4 f = *reinterpret_cast<const float4*>(in + i);
        ushort4 u;
        u.x = f2bf(f.x); u.y = f2bf(f.y); u.z = f2bf(f.z); u.w = f2bf(f.w);
        *reinterpret_cast<ushort4*>(out + i) = u;
        return;
    }
    if (b < 13312) {  // mask pack: 2048 blocks; block = (xb in [0,16), zb in [0,128))
        b -= 11264;
        const int xb = b & 15, zb = b >> 4;
        const int x  = xb * 256 + tid;
        const int z0 = zb * 32;
        unsigned w = 0;
        #pragma unroll 8
        for (int i = 0; i < 32; ++i)
            w |= (mask[(size_t)(z0 + i) * LXc + x] != 0 ? 1u : 0u) << i;
        bits[(size_t)x * (LZc / 32) + zb] = w;
        return;
    }
    // final block: reset the grid-barrier counter for this launch
    if (tid == 0) *barcnt = 0u;
}

// ---------------------------------------------------------------------------
extern "C" void kernel_launch(void* const* d_in, const int* in_sizes, int n_in,
                              void* d_out, int out_size, void* d_ws, size_t ws_size,
                              hipStream_t stream)
{
    const float* X    = (const float*)d_in[0];
    const float* Z    = (const float*)d_in[1];
    const int*   mask = (const int*)  d_in[2];
    const float* Wq   = (const float*)d_in[3];
    const float* bq   = (const float*)d_in[4];
    const float* Wk   = (const float*)d_in[5];
    const float* bk   = (const float*)d_in[6];
    const float* Wv   = (const float*)d_in[7];
    const float* bv   = (const float*)d_in[8];
    float* out = (float*)d_out;

    // 128 KiB dynamic LDS opt-in (once; host-side, not a stream op).
    static bool inited = false;
    if (!inited) {
        (void)hipFuncSetAttribute((const void*)fused_kernel,
                                  hipFuncAttributeMaxDynamicSharedMemorySize, 131072);
        inited = true;
    }

    // ws layout (peak live ~104 MB):
    //   prep-out:   XT 0-8, ZT 8-16, W 16-22, bits 38-40, barcnt @104M
    //   phase1-out: qT 22-30, kT 30-38, vB 64-72
    //   phase2/3:   sTb 72-104
    //   phase4-out: P 0-64 (overlays XT/ZT/W/qT/kT/bits — dead; the grid
    //               barrier's agent release+acquire fences provide the same
    //               coherence a kernel boundary would)
    char* ws = (char*)d_ws;
    ushort*   XT     = (ushort*)(ws);                   // 8 MB
    ushort*   ZT     = (ushort*)(ws + ( 8ull << 20));   // 8 MB
    ushort*   Wqb    = (ushort*)(ws + (16ull << 20));   // 2 MB
    ushort*   Wkb    = (ushort*)(ws + (18ull << 20));   // 2 MB
    ushort*   Wvb    = (ushort*)(ws + (20ull << 20));   // 2 MB
    ushort*   qT     = (ushort*)(ws + (22ull << 20));   // 8 MB
    ushort*   kT     = (ushort*)(ws + (30ull << 20));   // 8 MB
    unsigned* bits   = (unsigned*)(ws + (38ull << 20)); // 2 MB
    float*    P      = (float*) (ws);                   // 64 MB [phase 4]
    ushort*   vB     = (ushort*)(ws + (64ull << 20));   // 8 MB
    ushort*   sTb    = (ushort*)(ws + (72ull << 20));   // 32 MB
    unsigned* barcnt = (unsigned*)(ws + (104ull << 20));// 4 B

    prep_kernel<<<dim3(13313), 256, 0, stream>>>(X, Z, Wq, Wk, Wv, mask,
                                                 XT, ZT, Wqb, Wkb, Wvb, bits, barcnt);
    fused_kernel<<<dim3(256), 512, 131072, stream>>>(XT, ZT, Wqb, Wkb, Wvb,
                                                     bq, bk, bv, qT, kT, vB, sTb,
                                                     bits, P, barcnt, out);
}

// Round 7
// 291.720 us; speedup vs baseline: 1.4608x; 1.4608x over previous
//
#include <hip/hip_runtime.h>
#include <hip/hip_bf16.h>
#include <math.h>

constexpr int DXc = 1024;
constexpr int DZc = 1024;
constexpr int LXc = 4096;
constexpr int LZc = 4096;
constexpr int DAc = 1024;   // DATTN
constexpr int DOc = 1024;   // DOUT

typedef __attribute__((ext_vector_type(8))) short bf16x8;   // 8 bf16 = 4 VGPRs
typedef __attribute__((ext_vector_type(4))) float f32x4;
typedef __attribute__((ext_vector_type(8))) unsigned short us16x8;

__device__ __forceinline__ ushort f2bf(float f) {
    __hip_bfloat16 h = __float2bfloat16(f);
    return *reinterpret_cast<ushort*>(&h);
}
__device__ __forceinline__ float bflo(unsigned u) {
    return __builtin_bit_cast(float, u << 16);
}
__device__ __forceinline__ float bfhi(unsigned u) {
    return __builtin_bit_cast(float, u & 0xffff0000u);
}

enum BiasMode { BIAS_NONE, BIAS_M, BIAS_N };

#define SCHED0() __builtin_amdgcn_sched_barrier(0)
// Raw barrier, pinned on both sides so the compiler cannot move ds_reads /
// global_load_lds across it. NO waitcnt drain here — that is the whole point
// of the counted-vmcnt pipeline (T4).
#define BAR2()   do { SCHED0(); __builtin_amdgcn_s_barrier(); SCHED0(); } while (0)
#define LGKM0()  do { asm volatile("s_waitcnt lgkmcnt(0)" ::: "memory"); SCHED0(); } while (0)
#define VMCNT(n) do { asm volatile("s_waitcnt vmcnt(" #n ")" ::: "memory"); SCHED0(); } while (0)

// ---------------------------------------------------------------------------
// 256x256 tile, BK=64, 8 waves (2M x 4N), 8-phase counted-vmcnt schedule
// (T2 swizzle + T3/T4 + T5).  C[m,n] = sum_k A[m,k]*B[n,k], A,B K-major bf16.
// FROZEN — identical to the round-1 verified version (280.5 us config).
// ---------------------------------------------------------------------------
template<BiasMode BMODE, bool OUT_BF16, bool SPLIT>
__device__ __forceinline__ void gemm256(
    const ushort* __restrict__ A, const ushort* __restrict__ B,
    const float* __restrict__ bias, void* __restrict__ Cv,
    int M, int N, int K, int lda, int ldb, int ldc,
    int m0, int n0, int kbase, int zsplit, char* smem)
{
    const int tid  = threadIdx.x;
    const int wid  = tid >> 6, lane = tid & 63;
    const int wr   = wid >> 2, wc = wid & 3;          // 2M x 4N waves
    const int lrow = lane & 15, quad = lane >> 4;
    const int swz  = (lrow & 7) << 4;
    const int cx0  = (quad * 16) ^ swz;               // byte col, kstep 0
    const int cx1  = (64 + quad * 16) ^ swz;          // byte col, kstep 1
    const int raB  = (wr * 16 + lrow) * 128;          // A per-lane row base (bytes)
    const int rbB  = (wc * 16 + lrow) * 128;          // B per-lane row base (bytes)

    char* const Ab0 = smem;                 // A buf0: 32 KB ([256][64] bf16)
    char* const Ab1 = smem + 32768;         // A buf1
    char* const Bb0 = smem + 65536;         // B buf0
    char* const Bb1 = smem + 98304;         // B buf1

    // Stage one half-tile (128 rows x 64 cols) = 2 x global_load_lds(16B).
    // LDS dest linear (wave-uniform base + lane*16); global source inverse-swizzled.
    auto stage = [&](const ushort* __restrict__ Mat, int ld, int r0, int kc,
                     char* dstBuf, int h) {
        #pragma unroll
        for (int r = 0; r < 2; ++r) {
            const int q = h * 16384 + r * 8192 + wid * 1024 + lane * 16; // phys LDS byte
            const int p = q ^ (((q >> 7) & 7) << 4);                    // logical byte
            const ushort* g = Mat + (size_t)(r0 + (p >> 7)) * ld + kc + ((p & 127) >> 1);
            __builtin_amdgcn_global_load_lds(
                (const __attribute__((address_space(1))) void*)g,
                (__attribute__((address_space(3))) void*)(dstBuf + h * 16384 + r * 8192 + wid * 1024),
                16, 0, 0);
        }
    };

    f32x4  acc[8][4] = {};
    bf16x8 alo[4][2], ahi[4][2], blo[2][2], bhi[2][2];

    auto ldLo = [&](char* Abuf, char* Bbuf) {       // 12 ds_read_b128
        #pragma unroll
        for (int m = 0; m < 4; ++m) {
            alo[m][0] = *reinterpret_cast<const bf16x8*>(Abuf + m * 4096 + raB + cx0);
            alo[m][1] = *reinterpret_cast<const bf16x8*>(Abuf + m * 4096 + raB + cx1);
        }
        #pragma unroll
        for (int n = 0; n < 2; ++n) {
            blo[n][0] = *reinterpret_cast<const bf16x8*>(Bbuf + n * 8192 + rbB + cx0);
            blo[n][1] = *reinterpret_cast<const bf16x8*>(Bbuf + n * 8192 + rbB + cx1);
        }
    };
    auto ldAhi = [&](char* Abuf) {                  // 8 ds_read_b128
        #pragma unroll
        for (int m = 0; m < 4; ++m) {
            ahi[m][0] = *reinterpret_cast<const bf16x8*>(Abuf + (m + 4) * 4096 + raB + cx0);
            ahi[m][1] = *reinterpret_cast<const bf16x8*>(Abuf + (m + 4) * 4096 + raB + cx1);
        }
    };
    auto ldBhi = [&](char* Bbuf) {                  // 4 ds_read_b128
        #pragma unroll
        for (int n = 0; n < 2; ++n) {
            bhi[n][0] = *reinterpret_cast<const bf16x8*>(Bbuf + (n + 2) * 8192 + rbB + cx0);
            bhi[n][1] = *reinterpret_cast<const bf16x8*>(Bbuf + (n + 2) * 8192 + rbB + cx1);
        }
    };
    auto mmaQ = [&](bf16x8 (&a)[4][2], bf16x8 (&b)[2][2], int mh, int nh) {  // 16 MFMA
        __builtin_amdgcn_s_setprio(1);
        #pragma unroll
        for (int m = 0; m < 4; ++m)
            #pragma unroll
            for (int n = 0; n < 2; ++n) {
                f32x4& c = acc[mh * 4 + m][nh * 2 + n];
                c = __builtin_amdgcn_mfma_f32_16x16x32_bf16(a[m][0], b[n][0], c, 0, 0, 0);
                c = __builtin_amdgcn_mfma_f32_16x16x32_bf16(a[m][1], b[n][1], c, 0, 0, 0);
            }
        __builtin_amdgcn_s_setprio(0);
    };

    const int NIT = K >> 7;   // iterations; 2 K-tiles (BK=64) each

    // Prologue: tile0 {A0,B0,B1,A1} then tile1 {A0,B0,B1}; A1(tile1) comes in-loop p1.
    stage(A, lda, m0, kbase,      Ab0, 0);
    stage(B, ldb, n0, kbase,      Bb0, 0);
    stage(B, ldb, n0, kbase,      Bb0, 1);
    stage(A, lda, m0, kbase,      Ab0, 1);
    VMCNT(4);
    stage(A, lda, m0, kbase + 64, Ab1, 0);
    stage(B, ldb, n0, kbase + 64, Bb1, 0);
    stage(B, ldb, n0, kbase + 64, Bb1, 1);
    VMCNT(6);                 // ensures all of tile0 resident
    BAR2();

    #pragma unroll 1
    for (int it = 0; it < NIT; ++it) {
        const bool st  = (it < NIT - 1);
        const int kU   = kbase + (2 * it + 1) * 64;
        const int kT2  = kbase + (2 * it + 2) * 64;
        const int kT3  = kbase + (2 * it + 3) * 64;

        // ---- p1: tile T (buf0), quadrant (m-lo, n-lo)
        ldLo(Ab0, Bb0);
        stage(A, lda, m0, kU, Ab1, 1);                    // A1(U) - always needed
        asm volatile("s_waitcnt lgkmcnt(8)" ::: "memory");
        BAR2(); LGKM0();
        mmaQ(alo, blo, 0, 0);
        BAR2();
        // ---- p2: (m-lo, n-hi)
        ldBhi(Bb0);
        if (st) stage(A, lda, m0, kT2, Ab0, 0);           // A0(T+2)
        BAR2(); LGKM0();
        mmaQ(alo, bhi, 0, 1);
        BAR2();
        // ---- p3: (m-hi, n-hi)
        ldAhi(Ab0);
        if (st) stage(B, ldb, n0, kT2, Bb0, 0);           // B0(T+2)
        BAR2(); LGKM0();
        mmaQ(ahi, bhi, 1, 1);
        BAR2();
        // ---- p4: (m-hi, n-lo); once-per-K-tile vmcnt
        if (st) { stage(B, ldb, n0, kT2, Bb0, 1); VMCNT(6); }   // B1(T+2)
        else    { VMCNT(0); }                             // epilogue drain
        BAR2();
        mmaQ(ahi, blo, 1, 0);
        BAR2();
        // ---- p5: tile U (buf1), quadrant (m-lo, n-lo)
        ldLo(Ab1, Bb1);
        if (st) stage(A, lda, m0, kT2, Ab0, 1);           // A1(T+2)
        asm volatile("s_waitcnt lgkmcnt(8)" ::: "memory");
        BAR2(); LGKM0();
        mmaQ(alo, blo, 0, 0);
        BAR2();
        // ---- p6: (m-lo, n-hi)
        ldBhi(Bb1);
        if (st) stage(A, lda, m0, kT3, Ab1, 0);           // A0(T+3)
        BAR2(); LGKM0();
        mmaQ(alo, bhi, 0, 1);
        BAR2();
        // ---- p7: (m-hi, n-hi)
        ldAhi(Ab1);
        if (st) stage(B, ldb, n0, kT3, Bb1, 0);           // B0(T+3)
        BAR2(); LGKM0();
        mmaQ(ahi, bhi, 1, 1);
        BAR2();
        // ---- p8: (m-hi, n-lo)
        if (st) { stage(B, ldb, n0, kT3, Bb1, 1); VMCNT(6); }   // B1(T+3)
        else    { VMCNT(0); }
        BAR2();
        mmaQ(ahi, blo, 1, 0);
        BAR2();
    }

    // Epilogue: row = m0 + 32m + wr*16 + quad*4 + r ; col = n0 + 64n + wc*16 + lrow
    float*  Cf = (float*)Cv + (SPLIT ? (size_t)zsplit * (size_t)M * ldc : 0);
    ushort* Cb = (ushort*)Cv;
    #pragma unroll
    for (int m = 0; m < 8; ++m) {
        const int rowb = m0 + 32 * m + wr * 16 + quad * 4;
        #pragma unroll
        for (int r = 0; r < 4; ++r) {
            const int row = rowb + r;
            const float bm = (BMODE == BIAS_M) ? bias[row] : 0.0f;
            #pragma unroll
            for (int n = 0; n < 4; ++n) {
                const int col = n0 + 64 * n + wc * 16 + lrow;
                float v = acc[m][n][r] + ((BMODE == BIAS_N) ? bias[col] : bm);
                if (OUT_BF16) Cb[(size_t)row * ldc + col] = f2bf(v);
                else          Cf[(size_t)row * ldc + col] = v;
            }
        }
    }
}

// ---------------------------------------------------------------------------
// Batched projection GEMM: one dispatch for q, k, v (192 blocks of 512 thr).
// ---------------------------------------------------------------------------
__global__ __launch_bounds__(512, 2)
void proj256_kernel(const ushort* __restrict__ XT, const ushort* __restrict__ ZT,
                    const ushort* __restrict__ Wqb, const ushort* __restrict__ Wkb,
                    const ushort* __restrict__ Wvb,
                    const float* __restrict__ bq, const float* __restrict__ bk,
                    const float* __restrict__ bv,
                    ushort* __restrict__ qT, ushort* __restrict__ kT,
                    ushort* __restrict__ vB)
{
    extern __shared__ char smem[];
    int b = blockIdx.x;
    if (b < 64) {
        gemm256<BIAS_N, true, false>(XT, Wqb, bq, qT, LXc, DAc, DXc, DXc, DXc, DAc,
                                     (b >> 2) * 256, (b & 3) * 256, 0, 0, smem);
    } else if (b < 128) {
        b -= 64;
        gemm256<BIAS_N, true, false>(ZT, Wkb, bk, kT, LZc, DAc, DZc, DZc, DZc, DAc,
                                     (b >> 2) * 256, (b & 3) * 256, 0, 0, smem);
    } else {
        b -= 128;
        gemm256<BIAS_M, true, false>(Wvb, ZT, bv, vB, DOc, LZc, DZc, DZc, DZc, LZc,
                                     (b >> 4) * 256, (b & 15) * 256, 0, 0, smem);
    }
}

// Score GEMM: sTb[x,z] = sum_d qT[x,d] kT[z,d]  (bf16 out, no mask). 256 blocks.
__global__ __launch_bounds__(512, 2)
void score256_kernel(const ushort* __restrict__ qT, const ushort* __restrict__ kT,
                     ushort* __restrict__ sTb)
{
    extern __shared__ char smem[];
    const int b = blockIdx.x;
    gemm256<BIAS_NONE, true, false>(qT, kT, nullptr, sTb, LXc, LZc, DAc, DAc, DAc, LZc,
                                    (b >> 4) * 256, (b & 15) * 256, 0, 0, smem);
}

// Out GEMM split-K=4: P[z][o][x] fp32 partials. grid (16,4,4) = 256 blocks.
__global__ __launch_bounds__(512, 2)
void out256_kernel(const ushort* __restrict__ vB, const ushort* __restrict__ sTb,
                   float* __restrict__ P)
{
    extern __shared__ char smem[];
    gemm256<BIAS_NONE, false, true>(vB, sTb, nullptr, P, DOc, LXc, LZc / 4,
                                    LZc, LZc, LXc,
                                    blockIdx.y * 256, blockIdx.x * 256,
                                    blockIdx.z * (LZc / 4), blockIdx.z, smem);
}

// ---------------------------------------------------------------------------
// Prep (one dispatch, 5632 blocks):
//   b < 2048: 64x64 fp32->bf16 transpose via LDS, BOTH sides coalesced:
//             loads float4 (16 lanes x 16B = 256B/row), stores ushort8
//             (8 lanes x 16B = 128B/output-row). LDS ushort[64][70]
//             (pad 70: write phase covers all 32 banks; read worst 2-way=free).
//   b < 5120: weight fp32->bf16 convert (r1-proven float4/ushort4)
//   b < 5632: mask (LZ,LX) int -> bitsT[x][z/32], int4 loads (r2-proven)
// ---------------------------------------------------------------------------
__global__ __launch_bounds__(256)
void prep_kernel(const float* __restrict__ X, const float* __restrict__ Z,
                 const float* __restrict__ Wq, const float* __restrict__ Wk,
                 const float* __restrict__ Wv, const int* __restrict__ mask,
                 ushort* __restrict__ XT, ushort* __restrict__ ZT,
                 ushort* __restrict__ Wqb, ushort* __restrict__ Wkb,
                 ushort* __restrict__ Wvb, unsigned* __restrict__ bits)
{
    __shared__ ushort tile[64][70];
    const int tid = threadIdx.x;
    int b = blockIdx.x;

    if (b < 2048) {   // two transposes, 1024 blocks each: (R=1024, C=4096)
        const float* in  = (b < 1024) ? X : Z;
        ushort*      out = (b < 1024) ? XT : ZT;
        const int local = b & 1023;
        const int r0 = (local >> 6) * 64;           // 16 r-tiles
        const int c0 = (local & 63) * 64;           // 64 c-tiles
        // load: 4 passes, each thread one float4; 16 lanes = 256B contiguous
        const int lr = tid >> 4, cq = (tid & 15) * 4;
        #pragma unroll
        for (int p = 0; p < 4; ++p) {
            const float4 f = *reinterpret_cast<const float4*>(
                in + (size_t)(r0 + lr + 16 * p) * LXc + c0 + cq);
            ushort4 u;
            u.x = f2bf(f.x); u.y = f2bf(f.y); u.z = f2bf(f.z); u.w = f2bf(f.w);
            *reinterpret_cast<ushort4*>(&tile[lr + 16 * p][cq]) = u;
        }
        __syncthreads();
        // store: 2 passes; thread gathers 8 rows of one output row (col cc),
        // 8 lanes x ushort8 = 128B contiguous per output row
        const int rr = (tid & 7) * 8, ccb = tid >> 3;    // ccb in [0,32)
        #pragma unroll
        for (int p = 0; p < 2; ++p) {
            const int cc = ccb + 32 * p;
            us16x8 u8;
            #pragma unroll
            for (int j = 0; j < 8; ++j) u8[j] = tile[rr + j][cc];
            *reinterpret_cast<us16x8*>(out + (size_t)(c0 + cc) * DXc + r0 + rr) = u8;
        }
        return;
    }
    if (b < 5120) {   // three weight converts, 1024 blocks each (1M elems)
        b -= 2048;
        const float* in  = (b < 1024) ? Wq : (b < 2048) ? Wk : Wv;
        ushort*      out = (b < 1024) ? Wqb : (b < 2048) ? Wkb : Wvb;
        const int local = b & 1023;
        const size_t i = ((size_t)local * 256 + tid) * 4;
        float4 f = *reinterpret_cast<const float4*>(in + i);
        ushort4 u;
        u.x = f2bf(f.x); u.y = f2bf(f.y); u.z = f2bf(f.z); u.w = f2bf(f.w);
        *reinterpret_cast<ushort4*>(out + i) = u;
        return;
    }
    // mask pack: 512 blocks; block = (xb in [0,4), zb in [0,128)); int4 loads
    b -= 5120;
    const int xb = b & 3, zb = b >> 2;
    const int x  = xb * 1024 + tid * 4;
    const int* mp = mask + (size_t)(zb * 32) * LXc + x;
    unsigned w0 = 0, w1 = 0, w2 = 0, w3 = 0;
    #pragma unroll 8
    for (int i = 0; i < 32; ++i) {
        const int4 m = *reinterpret_cast<const int4*>(mp + (size_t)i * LXc);
        w0 |= (m.x != 0 ? 1u : 0u) << i;
        w1 |= (m.y != 0 ? 1u : 0u) << i;
        w2 |= (m.z != 0 ? 1u : 0u) << i;
        w3 |= (m.w != 0 ? 1u : 0u) << i;
    }
    bits[(size_t)(x + 0) * (LZc / 32) + zb] = w0;
    bits[(size_t)(x + 1) * (LZc / 32) + zb] = w1;
    bits[(size_t)(x + 2) * (LZc / 32) + zb] = w2;
    bits[(size_t)(x + 3) * (LZc / 32) + zb] = w3;
}

// ---------------------------------------------------------------------------
// Row softmax over bf16 sTb (LX x LZ) with packed mask bits; scale 1/32,
// masked -> -1000/32; softmax over the row; bf16 in place.  (r1 version)
// ---------------------------------------------------------------------------
__global__ __launch_bounds__(256)
void softmax_kernel(ushort* __restrict__ sTb, const unsigned* __restrict__ bits)
{
    const int x   = blockIdx.x;
    const int tid = threadIdx.x;
    ushort* row = sTb + (size_t)x * LZc;
    constexpr float scale = 1.0f / 32.0f;   // 1/sqrt(1024)
    constexpr float MASKV = -1000.0f / 32.0f;

    float v[16];
    float mx = -1e30f;
    #pragma unroll
    for (int r = 0; r < 2; ++r) {
        const uint4 pk = *reinterpret_cast<const uint4*>(row + (size_t)(r * 256 + tid) * 8);
        const unsigned* w = reinterpret_cast<const unsigned*>(&pk);
        const unsigned mb = (bits[(size_t)x * 128 + r * 64 + (tid >> 2)] >> ((tid & 3) * 8)) & 0xffu;
        #pragma unroll
        for (int j = 0; j < 4; ++j) {
            const float lo = ((mb >> (2 * j))     & 1u) ? bflo(w[j]) * scale : MASKV;
            const float hi = ((mb >> (2 * j + 1)) & 1u) ? bfhi(w[j]) * scale : MASKV;
            v[r * 8 + 2 * j]     = lo;
            v[r * 8 + 2 * j + 1] = hi;
            mx = fmaxf(mx, fmaxf(lo, hi));
        }
    }
    __shared__ float redmax[4];
    #pragma unroll
    for (int off = 32; off > 0; off >>= 1)
        mx = fmaxf(mx, __shfl_down(mx, off, 64));
    if ((tid & 63) == 0) redmax[tid >> 6] = mx;
    __syncthreads();
    mx = fmaxf(fmaxf(redmax[0], redmax[1]), fmaxf(redmax[2], redmax[3]));

    float sum = 0.0f;
    #pragma unroll
    for (int i = 0; i < 16; ++i) {
        v[i] = __expf(v[i] - mx);
        sum += v[i];
    }
    __shared__ float redsum[4];
    #pragma unroll
    for (int off = 32; off > 0; off >>= 1)
        sum += __shfl_down(sum, off, 64);
    if ((tid & 63) == 0) redsum[tid >> 6] = sum;
    __syncthreads();
    sum = redsum[0] + redsum[1] + redsum[2] + redsum[3];
    const float inv = 1.0f / sum;

    #pragma unroll
    for (int r = 0; r < 2; ++r) {
        uint4 pk;
        unsigned* w = reinterpret_cast<unsigned*>(&pk);
        #pragma unroll
        for (int j = 0; j < 4; ++j) {
            const unsigned lo = f2bf(v[r * 8 + 2 * j] * inv);
            const unsigned hi = f2bf(v[r * 8 + 2 * j + 1] * inv);
            w[j] = lo | (hi << 16);
        }
        *reinterpret_cast<uint4*>(row + (size_t)(r * 256 + tid) * 8) = pk;
    }
}

// Sum 4 fp32 partials -> fp32 out
__global__ __launch_bounds__(256)
void reduce_kernel(const float* __restrict__ P, float* __restrict__ out)
{
    constexpr size_t total = (size_t)DOc * LXc;
    const size_t i = ((size_t)blockIdx.x * 256 + threadIdx.x) * 4;
    float4 s = *reinterpret_cast<const float4*>(P + i);
    #pragma unroll
    for (int p = 1; p < 4; ++p) {
        const float4 t = *reinterpret_cast<const float4*>(P + (size_t)p * total + i);
        s.x += t.x; s.y += t.y; s.z += t.z; s.w += t.w;
    }
    *reinterpret_cast<float4*>(out + i) = s;
}

// ---------------------------------------------------------------------------
extern "C" void kernel_launch(void* const* d_in, const int* in_sizes, int n_in,
                              void* d_out, int out_size, void* d_ws, size_t ws_size,
                              hipStream_t stream)
{
    const float* X    = (const float*)d_in[0];
    const float* Z    = (const float*)d_in[1];
    const int*   mask = (const int*)  d_in[2];
    const float* Wq   = (const float*)d_in[3];
    const float* bq   = (const float*)d_in[4];
    const float* Wk   = (const float*)d_in[5];
    const float* bk   = (const float*)d_in[6];
    const float* Wv   = (const float*)d_in[7];
    const float* bv   = (const float*)d_in[8];
    float* out = (float*)d_out;

    // 128 KiB dynamic LDS opt-in (once; host-side, not a stream op).
    static bool inited = false;
    if (!inited) {
        (void)hipFuncSetAttribute((const void*)proj256_kernel,
                                  hipFuncAttributeMaxDynamicSharedMemorySize, 131072);
        (void)hipFuncSetAttribute((const void*)score256_kernel,
                                  hipFuncAttributeMaxDynamicSharedMemorySize, 131072);
        (void)hipFuncSetAttribute((const void*)out256_kernel,
                                  hipFuncAttributeMaxDynamicSharedMemorySize, 131072);
        inited = true;
    }

    // ws layout (106 MB). P (64 MB at offset 0) OVERLAYS XT/ZT/W/qT/kT --
    // all dead by the time the out GEMM writes P.  (r1-proven layout)
    char* ws = (char*)d_ws;
    ushort*   XT   = (ushort*)(ws);                   // 8 MB   [dead after proj]
    ushort*   ZT   = (ushort*)(ws + ( 8ull << 20));   // 8 MB   [dead after proj]
    ushort*   Wqb  = (ushort*)(ws + (16ull << 20));   // 2 MB   [dead after proj]
    ushort*   Wkb  = (ushort*)(ws + (18ull << 20));   // 2 MB   [dead after proj]
    ushort*   Wvb  = (ushort*)(ws + (20ull << 20));   // 2 MB   [dead after proj]
    ushort*   qT   = (ushort*)(ws + (22ull << 20));   // 8 MB   [dead after score]
    ushort*   kT   = (ushort*)(ws + (30ull << 20));   // 8 MB   [dead after score]
    float*    P    = (float*) (ws);                   // 64 MB  [out partials]
    ushort*   vB   = (ushort*)(ws + (64ull << 20));   // 8 MB
    ushort*   sTb  = (ushort*)(ws + (72ull << 20));   // 32 MB
    unsigned* bits = (unsigned*)(ws + (104ull << 20));// 2 MB

    prep_kernel<<<dim3(5632), 256, 0, stream>>>(X, Z, Wq, Wk, Wv, mask,
                                                XT, ZT, Wqb, Wkb, Wvb, bits);
    proj256_kernel<<<dim3(192), 512, 131072, stream>>>(XT, ZT, Wqb, Wkb, Wvb,
                                                       bq, bk, bv, qT, kT, vB);
    score256_kernel<<<dim3(256), 512, 131072, stream>>>(qT, kT, sTb);
    softmax_kernel<<<dim3(LXc), 256, 0, stream>>>(sTb, bits);
    out256_kernel<<<dim3(16, 4, 4), 512, 131072, stream>>>(vB, sTb, P);
    reduce_kernel<<<dim3(DOc * LXc / 1024), 256, 0, stream>>>(P, out);
}

// Round 8
// 280.004 us; speedup vs baseline: 1.5220x; 1.0418x over previous
//
#include <hip/hip_runtime.h>
#include <hip/hip_bf16.h>
#include <math.h>

constexpr int DXc = 1024;
constexpr int DZc = 1024;
constexpr int LXc = 4096;
constexpr int LZc = 4096;
constexpr int DAc = 1024;   // DATTN
constexpr int DOc = 1024;   // DOUT

typedef __attribute__((ext_vector_type(8))) short bf16x8;   // 8 bf16 = 4 VGPRs
typedef __attribute__((ext_vector_type(4))) float f32x4;
typedef __attribute__((ext_vector_type(8))) _Float16 f16x8;

__device__ __forceinline__ ushort f2bf(float f) {
    __hip_bfloat16 h = __float2bfloat16(f);
    return *reinterpret_cast<ushort*>(&h);
}
__device__ __forceinline__ float bflo(unsigned u) {
    return __builtin_bit_cast(float, u << 16);
}
__device__ __forceinline__ float bfhi(unsigned u) {
    return __builtin_bit_cast(float, u & 0xffff0000u);
}

enum BiasMode { BIAS_NONE, BIAS_M, BIAS_N };

#define SCHED0() __builtin_amdgcn_sched_barrier(0)
// Raw barrier, pinned on both sides so the compiler cannot move ds_reads /
// global_load_lds across it. NO waitcnt drain here — that is the whole point
// of the counted-vmcnt pipeline (T4).
#define BAR2()   do { SCHED0(); __builtin_amdgcn_s_barrier(); SCHED0(); } while (0)
#define LGKM0()  do { asm volatile("s_waitcnt lgkmcnt(0)" ::: "memory"); SCHED0(); } while (0)
#define VMCNT(n) do { asm volatile("s_waitcnt vmcnt(" #n ")" ::: "memory"); SCHED0(); } while (0)

// ---------------------------------------------------------------------------
// 256x256 tile, BK=64, 8 waves (2M x 4N), 8-phase counted-vmcnt schedule
// (T2 swizzle + T3/T4 + T5).  C[m,n] = sum_k A[m,k]*B[n,k], A,B K-major bf16.
// Main loop FROZEN (round-1 verified). SPLIT epilogue now stores fp16
// partials (halves P traffic; fp16 rel-err 2^-11 negligible vs bf16 inputs).
// ---------------------------------------------------------------------------
template<BiasMode BMODE, bool OUT_BF16, bool SPLIT>
__device__ __forceinline__ void gemm256(
    const ushort* __restrict__ A, const ushort* __restrict__ B,
    const float* __restrict__ bias, void* __restrict__ Cv,
    int M, int N, int K, int lda, int ldb, int ldc,
    int m0, int n0, int kbase, int zsplit, char* smem)
{
    const int tid  = threadIdx.x;
    const int wid  = tid >> 6, lane = tid & 63;
    const int wr   = wid >> 2, wc = wid & 3;          // 2M x 4N waves
    const int lrow = lane & 15, quad = lane >> 4;
    const int swz  = (lrow & 7) << 4;
    const int cx0  = (quad * 16) ^ swz;               // byte col, kstep 0
    const int cx1  = (64 + quad * 16) ^ swz;          // byte col, kstep 1
    const int raB  = (wr * 16 + lrow) * 128;          // A per-lane row base (bytes)
    const int rbB  = (wc * 16 + lrow) * 128;          // B per-lane row base (bytes)

    char* const Ab0 = smem;                 // A buf0: 32 KB ([256][64] bf16)
    char* const Ab1 = smem + 32768;         // A buf1
    char* const Bb0 = smem + 65536;         // B buf0
    char* const Bb1 = smem + 98304;         // B buf1

    // Stage one half-tile (128 rows x 64 cols) = 2 x global_load_lds(16B).
    // LDS dest linear (wave-uniform base + lane*16); global source inverse-swizzled.
    auto stage = [&](const ushort* __restrict__ Mat, int ld, int r0, int kc,
                     char* dstBuf, int h) {
        #pragma unroll
        for (int r = 0; r < 2; ++r) {
            const int q = h * 16384 + r * 8192 + wid * 1024 + lane * 16; // phys LDS byte
            const int p = q ^ (((q >> 7) & 7) << 4);                    // logical byte
            const ushort* g = Mat + (size_t)(r0 + (p >> 7)) * ld + kc + ((p & 127) >> 1);
            __builtin_amdgcn_global_load_lds(
                (const __attribute__((address_space(1))) void*)g,
                (__attribute__((address_space(3))) void*)(dstBuf + h * 16384 + r * 8192 + wid * 1024),
                16, 0, 0);
        }
    };

    f32x4  acc[8][4] = {};
    bf16x8 alo[4][2], ahi[4][2], blo[2][2], bhi[2][2];

    auto ldLo = [&](char* Abuf, char* Bbuf) {       // 12 ds_read_b128
        #pragma unroll
        for (int m = 0; m < 4; ++m) {
            alo[m][0] = *reinterpret_cast<const bf16x8*>(Abuf + m * 4096 + raB + cx0);
            alo[m][1] = *reinterpret_cast<const bf16x8*>(Abuf + m * 4096 + raB + cx1);
        }
        #pragma unroll
        for (int n = 0; n < 2; ++n) {
            blo[n][0] = *reinterpret_cast<const bf16x8*>(Bbuf + n * 8192 + rbB + cx0);
            blo[n][1] = *reinterpret_cast<const bf16x8*>(Bbuf + n * 8192 + rbB + cx1);
        }
    };
    auto ldAhi = [&](char* Abuf) {                  // 8 ds_read_b128
        #pragma unroll
        for (int m = 0; m < 4; ++m) {
            ahi[m][0] = *reinterpret_cast<const bf16x8*>(Abuf + (m + 4) * 4096 + raB + cx0);
            ahi[m][1] = *reinterpret_cast<const bf16x8*>(Abuf + (m + 4) * 4096 + raB + cx1);
        }
    };
    auto ldBhi = [&](char* Bbuf) {                  // 4 ds_read_b128
        #pragma unroll
        for (int n = 0; n < 2; ++n) {
            bhi[n][0] = *reinterpret_cast<const bf16x8*>(Bbuf + (n + 2) * 8192 + rbB + cx0);
            bhi[n][1] = *reinterpret_cast<const bf16x8*>(Bbuf + (n + 2) * 8192 + rbB + cx1);
        }
    };
    auto mmaQ = [&](bf16x8 (&a)[4][2], bf16x8 (&b)[2][2], int mh, int nh) {  // 16 MFMA
        __builtin_amdgcn_s_setprio(1);
        #pragma unroll
        for (int m = 0; m < 4; ++m)
            #pragma unroll
            for (int n = 0; n < 2; ++n) {
                f32x4& c = acc[mh * 4 + m][nh * 2 + n];
                c = __builtin_amdgcn_mfma_f32_16x16x32_bf16(a[m][0], b[n][0], c, 0, 0, 0);
                c = __builtin_amdgcn_mfma_f32_16x16x32_bf16(a[m][1], b[n][1], c, 0, 0, 0);
            }
        __builtin_amdgcn_s_setprio(0);
    };

    const int NIT = K >> 7;   // iterations; 2 K-tiles (BK=64) each

    // Prologue: tile0 {A0,B0,B1,A1} then tile1 {A0,B0,B1}; A1(tile1) comes in-loop p1.
    stage(A, lda, m0, kbase,      Ab0, 0);
    stage(B, ldb, n0, kbase,      Bb0, 0);
    stage(B, ldb, n0, kbase,      Bb0, 1);
    stage(A, lda, m0, kbase,      Ab0, 1);
    VMCNT(4);
    stage(A, lda, m0, kbase + 64, Ab1, 0);
    stage(B, ldb, n0, kbase + 64, Bb1, 0);
    stage(B, ldb, n0, kbase + 64, Bb1, 1);
    VMCNT(6);                 // ensures all of tile0 resident
    BAR2();

    #pragma unroll 1
    for (int it = 0; it < NIT; ++it) {
        const bool st  = (it < NIT - 1);
        const int kU   = kbase + (2 * it + 1) * 64;
        const int kT2  = kbase + (2 * it + 2) * 64;
        const int kT3  = kbase + (2 * it + 3) * 64;

        // ---- p1: tile T (buf0), quadrant (m-lo, n-lo)
        ldLo(Ab0, Bb0);
        stage(A, lda, m0, kU, Ab1, 1);                    // A1(U) - always needed
        asm volatile("s_waitcnt lgkmcnt(8)" ::: "memory");
        BAR2(); LGKM0();
        mmaQ(alo, blo, 0, 0);
        BAR2();
        // ---- p2: (m-lo, n-hi)
        ldBhi(Bb0);
        if (st) stage(A, lda, m0, kT2, Ab0, 0);           // A0(T+2)
        BAR2(); LGKM0();
        mmaQ(alo, bhi, 0, 1);
        BAR2();
        // ---- p3: (m-hi, n-hi)
        ldAhi(Ab0);
        if (st) stage(B, ldb, n0, kT2, Bb0, 0);           // B0(T+2)
        BAR2(); LGKM0();
        mmaQ(ahi, bhi, 1, 1);
        BAR2();
        // ---- p4: (m-hi, n-lo); once-per-K-tile vmcnt
        if (st) { stage(B, ldb, n0, kT2, Bb0, 1); VMCNT(6); }   // B1(T+2)
        else    { VMCNT(0); }                             // epilogue drain
        BAR2();
        mmaQ(ahi, blo, 1, 0);
        BAR2();
        // ---- p5: tile U (buf1), quadrant (m-lo, n-lo)
        ldLo(Ab1, Bb1);
        if (st) stage(A, lda, m0, kT2, Ab0, 1);           // A1(T+2)
        asm volatile("s_waitcnt lgkmcnt(8)" ::: "memory");
        BAR2(); LGKM0();
        mmaQ(alo, blo, 0, 0);
        BAR2();
        // ---- p6: (m-lo, n-hi)
        ldBhi(Bb1);
        if (st) stage(A, lda, m0, kT3, Ab1, 0);           // A0(T+3)
        BAR2(); LGKM0();
        mmaQ(alo, bhi, 0, 1);
        BAR2();
        // ---- p7: (m-hi, n-hi)
        ldAhi(Ab1);
        if (st) stage(B, ldb, n0, kT3, Bb1, 0);           // B0(T+3)
        BAR2(); LGKM0();
        mmaQ(ahi, bhi, 1, 1);
        BAR2();
        // ---- p8: (m-hi, n-lo)
        if (st) { stage(B, ldb, n0, kT3, Bb1, 1); VMCNT(6); }   // B1(T+3)
        else    { VMCNT(0); }
        BAR2();
        mmaQ(ahi, blo, 1, 0);
        BAR2();
    }

    // Epilogue: row = m0 + 32m + wr*16 + quad*4 + r ; col = n0 + 64n + wc*16 + lrow
    _Float16* Ch = (_Float16*)Cv + (SPLIT ? (size_t)zsplit * (size_t)M * ldc : 0);
    ushort*   Cb = (ushort*)Cv;
    #pragma unroll
    for (int m = 0; m < 8; ++m) {
        const int rowb = m0 + 32 * m + wr * 16 + quad * 4;
        #pragma unroll
        for (int r = 0; r < 4; ++r) {
            const int row = rowb + r;
            const float bm = (BMODE == BIAS_M) ? bias[row] : 0.0f;
            #pragma unroll
            for (int n = 0; n < 4; ++n) {
                const int col = n0 + 64 * n + wc * 16 + lrow;
                float v = acc[m][n][r] + ((BMODE == BIAS_N) ? bias[col] : bm);
                if (OUT_BF16) Cb[(size_t)row * ldc + col] = f2bf(v);
                else          Ch[(size_t)row * ldc + col] = (_Float16)v;
            }
        }
    }
}

// ---------------------------------------------------------------------------
// Batched projection GEMM + mask pack: one dispatch, 256 blocks of 512 thr.
//   b <  64: qT   b < 128: kT   b < 192: vB
//   b < 256: mask (LZ,LX) int -> bitsT[x][z/32] on the 64 otherwise-idle CUs
//            (mask bits are first consumed by softmax, 2 dispatches later).
// ---------------------------------------------------------------------------
__global__ __launch_bounds__(512, 2)
void proj256_kernel(const ushort* __restrict__ XT, const ushort* __restrict__ ZT,
                    const ushort* __restrict__ Wqb, const ushort* __restrict__ Wkb,
                    const ushort* __restrict__ Wvb,
                    const float* __restrict__ bq, const float* __restrict__ bk,
                    const float* __restrict__ bv,
                    ushort* __restrict__ qT, ushort* __restrict__ kT,
                    ushort* __restrict__ vB,
                    const int* __restrict__ mask, unsigned* __restrict__ bits)
{
    extern __shared__ char smem[];
    int b = blockIdx.x;
    if (b < 64) {
        gemm256<BIAS_N, true, false>(XT, Wqb, bq, qT, LXc, DAc, DXc, DXc, DXc, DAc,
                                     (b >> 2) * 256, (b & 3) * 256, 0, 0, smem);
    } else if (b < 128) {
        b -= 64;
        gemm256<BIAS_N, true, false>(ZT, Wkb, bk, kT, LZc, DAc, DZc, DZc, DZc, DAc,
                                     (b >> 2) * 256, (b & 3) * 256, 0, 0, smem);
    } else if (b < 192) {
        b -= 128;
        gemm256<BIAS_M, true, false>(Wvb, ZT, bv, vB, DOc, LZc, DZc, DZc, DZc, LZc,
                                     (b >> 4) * 256, (b & 15) * 256, 0, 0, smem);
    } else {
        // mask pack: 64 blocks x 512 thr; int4 loads across x, 32 z-rows/word.
        const int mb  = b - 192;            // [0,64)
        const int tid = threadIdx.x;        // [0,512)
        #pragma unroll 1
        for (int zi = 0; zi < 2; ++zi) {
            const int zb = mb * 2 + zi;     // [0,128)
            #pragma unroll 1
            for (int rep = 0; rep < 2; ++rep) {
                const int x = (rep * 512 + tid) * 4;   // [0,4096) step 4
                const int* mp = mask + (size_t)(zb * 32) * LXc + x;
                unsigned w0 = 0, w1 = 0, w2 = 0, w3 = 0;
                #pragma unroll 8
                for (int i = 0; i < 32; ++i) {
                    const int4 m = *reinterpret_cast<const int4*>(mp + (size_t)i * LXc);
                    w0 |= (m.x != 0 ? 1u : 0u) << i;
                    w1 |= (m.y != 0 ? 1u : 0u) << i;
                    w2 |= (m.z != 0 ? 1u : 0u) << i;
                    w3 |= (m.w != 0 ? 1u : 0u) << i;
                }
                bits[(size_t)(x + 0) * (LZc / 32) + zb] = w0;
                bits[(size_t)(x + 1) * (LZc / 32) + zb] = w1;
                bits[(size_t)(x + 2) * (LZc / 32) + zb] = w2;
                bits[(size_t)(x + 3) * (LZc / 32) + zb] = w3;
            }
        }
    }
}

// Score GEMM: sTb[x,z] = sum_d qT[x,d] kT[z,d]  (bf16 out, no mask). 256 blocks.
__global__ __launch_bounds__(512, 2)
void score256_kernel(const ushort* __restrict__ qT, const ushort* __restrict__ kT,
                     ushort* __restrict__ sTb)
{
    extern __shared__ char smem[];
    const int b = blockIdx.x;
    gemm256<BIAS_NONE, true, false>(qT, kT, nullptr, sTb, LXc, LZc, DAc, DAc, DAc, LZc,
                                    (b >> 4) * 256, (b & 15) * 256, 0, 0, smem);
}

// Out GEMM split-K=4: P[z][o][x] fp16 partials. grid (16,4,4) = 256 blocks.
__global__ __launch_bounds__(512, 2)
void out256_kernel(const ushort* __restrict__ vB, const ushort* __restrict__ sTb,
                   _Float16* __restrict__ P)
{
    extern __shared__ char smem[];
    gemm256<BIAS_NONE, false, true>(vB, sTb, nullptr, P, DOc, LXc, LZc / 4,
                                    LZc, LZc, LXc,
                                    blockIdx.y * 256, blockIdx.x * 256,
                                    blockIdx.z * (LZc / 4), blockIdx.z, smem);
}

// ---------------------------------------------------------------------------
// Prep (one dispatch, 11264 blocks) — round-1 measured-best, FROZEN:
// X->XT bf16 LDS transpose, Z->ZT, Wq/Wk/Wv fp32->bf16. (Mask pack moved
// into proj's idle blocks.)
// ---------------------------------------------------------------------------
__global__ __launch_bounds__(256)
void prep_kernel(const float* __restrict__ X, const float* __restrict__ Z,
                 const float* __restrict__ Wq, const float* __restrict__ Wk,
                 const float* __restrict__ Wv,
                 ushort* __restrict__ XT, ushort* __restrict__ ZT,
                 ushort* __restrict__ Wqb, ushort* __restrict__ Wkb,
                 ushort* __restrict__ Wvb)
{
    __shared__ float tile[32][33];
    const int tid = threadIdx.x;
    int b = blockIdx.x;

    if (b < 8192) {   // two transposes, 4096 blocks each: (R=1024, C=4096)
        const float* in  = (b < 4096) ? X : Z;
        ushort*      out = (b < 4096) ? XT : ZT;
        const int local = b & 4095;
        const int bx = local & 127, by = local >> 7;     // C/32=128 tiles in x
        const int c0 = bx * 32, r0 = by * 32;
        const int tx = tid & 31, ty = tid >> 5;          // 32 x 8
        #pragma unroll
        for (int i = 0; i < 32; i += 8)
            tile[ty + i][tx] = in[(size_t)(r0 + ty + i) * LXc + c0 + tx];
        __syncthreads();
        #pragma unroll
        for (int i = 0; i < 32; i += 8)
            out[(size_t)(c0 + ty + i) * DXc + r0 + tx] = f2bf(tile[tx][ty + i]);
        return;
    }
    // three weight converts, 1024 blocks each (1M elems)
    b -= 8192;
    const float* in  = (b < 1024) ? Wq : (b < 2048) ? Wk : Wv;
    ushort*      out = (b < 1024) ? Wqb : (b < 2048) ? Wkb : Wvb;
    const int local = b & 1023;
    const size_t i = ((size_t)local * 256 + tid) * 4;
    float4 f = *reinterpret_cast<const float4*>(in + i);
    ushort4 u;
    u.x = f2bf(f.x); u.y = f2bf(f.y); u.z = f2bf(f.z); u.w = f2bf(f.w);
    *reinterpret_cast<ushort4*>(out + i) = u;
}

// ---------------------------------------------------------------------------
// Row softmax over bf16 sTb (LX x LZ) with packed mask bits; scale 1/32,
// masked -> -1000/32; softmax over the row; bf16 in place.  (r1 version)
// ---------------------------------------------------------------------------
__global__ __launch_bounds__(256)
void softmax_kernel(ushort* __restrict__ sTb, const unsigned* __restrict__ bits)
{
    const int x   = blockIdx.x;
    const int tid = threadIdx.x;
    ushort* row = sTb + (size_t)x * LZc;
    constexpr float scale = 1.0f / 32.0f;   // 1/sqrt(1024)
    constexpr float MASKV = -1000.0f / 32.0f;

    float v[16];
    float mx = -1e30f;
    #pragma unroll
    for (int r = 0; r < 2; ++r) {
        const uint4 pk = *reinterpret_cast<const uint4*>(row + (size_t)(r * 256 + tid) * 8);
        const unsigned* w = reinterpret_cast<const unsigned*>(&pk);
        const unsigned mb = (bits[(size_t)x * 128 + r * 64 + (tid >> 2)] >> ((tid & 3) * 8)) & 0xffu;
        #pragma unroll
        for (int j = 0; j < 4; ++j) {
            const float lo = ((mb >> (2 * j))     & 1u) ? bflo(w[j]) * scale : MASKV;
            const float hi = ((mb >> (2 * j + 1)) & 1u) ? bfhi(w[j]) * scale : MASKV;
            v[r * 8 + 2 * j]     = lo;
            v[r * 8 + 2 * j + 1] = hi;
            mx = fmaxf(mx, fmaxf(lo, hi));
        }
    }
    __shared__ float redmax[4];
    #pragma unroll
    for (int off = 32; off > 0; off >>= 1)
        mx = fmaxf(mx, __shfl_down(mx, off, 64));
    if ((tid & 63) == 0) redmax[tid >> 6] = mx;
    __syncthreads();
    mx = fmaxf(fmaxf(redmax[0], redmax[1]), fmaxf(redmax[2], redmax[3]));

    float sum = 0.0f;
    #pragma unroll
    for (int i = 0; i < 16; ++i) {
        v[i] = __expf(v[i] - mx);
        sum += v[i];
    }
    __shared__ float redsum[4];
    #pragma unroll
    for (int off = 32; off > 0; off >>= 1)
        sum += __shfl_down(sum, off, 64);
    if ((tid & 63) == 0) redsum[tid >> 6] = sum;
    __syncthreads();
    sum = redsum[0] + redsum[1] + redsum[2] + redsum[3];
    const float inv = 1.0f / sum;

    #pragma unroll
    for (int r = 0; r < 2; ++r) {
        uint4 pk;
        unsigned* w = reinterpret_cast<unsigned*>(&pk);
        #pragma unroll
        for (int j = 0; j < 4; ++j) {
            const unsigned lo = f2bf(v[r * 8 + 2 * j] * inv);
            const unsigned hi = f2bf(v[r * 8 + 2 * j + 1] * inv);
            w[j] = lo | (hi << 16);
        }
        *reinterpret_cast<uint4*>(row + (size_t)(r * 256 + tid) * 8) = pk;
    }
}

// Sum 4 fp16 partial planes -> fp32 out. 8 elems/thread, 2048 blocks.
__global__ __launch_bounds__(256)
void reduce_kernel(const _Float16* __restrict__ P, float* __restrict__ out)
{
    constexpr size_t total = (size_t)DOc * LXc;
    const size_t i = ((size_t)blockIdx.x * 256 + threadIdx.x) * 8;
    float s[8] = {};
    #pragma unroll
    for (int p = 0; p < 4; ++p) {
        const f16x8 t = *reinterpret_cast<const f16x8*>(P + (size_t)p * total + i);
        #pragma unroll
        for (int j = 0; j < 8; ++j) s[j] += (float)t[j];
    }
    float4 o0 = {s[0], s[1], s[2], s[3]};
    float4 o1 = {s[4], s[5], s[6], s[7]};
    *reinterpret_cast<float4*>(out + i)     = o0;
    *reinterpret_cast<float4*>(out + i + 4) = o1;
}

// ---------------------------------------------------------------------------
extern "C" void kernel_launch(void* const* d_in, const int* in_sizes, int n_in,
                              void* d_out, int out_size, void* d_ws, size_t ws_size,
                              hipStream_t stream)
{
    const float* X    = (const float*)d_in[0];
    const float* Z    = (const float*)d_in[1];
    const int*   mask = (const int*)  d_in[2];
    const float* Wq   = (const float*)d_in[3];
    const float* bq   = (const float*)d_in[4];
    const float* Wk   = (const float*)d_in[5];
    const float* bk   = (const float*)d_in[6];
    const float* Wv   = (const float*)d_in[7];
    const float* bv   = (const float*)d_in[8];
    float* out = (float*)d_out;

    // 128 KiB dynamic LDS opt-in (once; host-side, not a stream op).
    static bool inited = false;
    if (!inited) {
        (void)hipFuncSetAttribute((const void*)proj256_kernel,
                                  hipFuncAttributeMaxDynamicSharedMemorySize, 131072);
        (void)hipFuncSetAttribute((const void*)score256_kernel,
                                  hipFuncAttributeMaxDynamicSharedMemorySize, 131072);
        (void)hipFuncSetAttribute((const void*)out256_kernel,
                                  hipFuncAttributeMaxDynamicSharedMemorySize, 131072);
        inited = true;
    }

    // ws layout (106 MB). P (32 MB fp16 at offset 0) OVERLAYS XT/ZT/W/qT and
    // the first 2 MB of kT — all dead by the time the out GEMM writes P.
    char* ws = (char*)d_ws;
    ushort*   XT   = (ushort*)(ws);                   // 8 MB   [dead after proj]
    ushort*   ZT   = (ushort*)(ws + ( 8ull << 20));   // 8 MB   [dead after proj]
    ushort*   Wqb  = (ushort*)(ws + (16ull << 20));   // 2 MB   [dead after proj]
    ushort*   Wkb  = (ushort*)(ws + (18ull << 20));   // 2 MB   [dead after proj]
    ushort*   Wvb  = (ushort*)(ws + (20ull << 20));   // 2 MB   [dead after proj]
    ushort*   qT   = (ushort*)(ws + (22ull << 20));   // 8 MB   [dead after score]
    ushort*   kT   = (ushort*)(ws + (30ull << 20));   // 8 MB   [dead after score]
    _Float16* P    = (_Float16*)(ws);                 // 32 MB  [out partials]
    ushort*   vB   = (ushort*)(ws + (64ull << 20));   // 8 MB
    ushort*   sTb  = (ushort*)(ws + (72ull << 20));   // 32 MB
    unsigned* bits = (unsigned*)(ws + (104ull << 20));// 2 MB   [live: proj->softmax]

    prep_kernel<<<dim3(11264), 256, 0, stream>>>(X, Z, Wq, Wk, Wv,
                                                 XT, ZT, Wqb, Wkb, Wvb);
    proj256_kernel<<<dim3(256), 512, 131072, stream>>>(XT, ZT, Wqb, Wkb, Wvb,
                                                       bq, bk, bv, qT, kT, vB,
                                                       mask, bits);
    score256_kernel<<<dim3(256), 512, 131072, stream>>>(qT, kT, sTb);
    softmax_kernel<<<dim3(LXc), 256, 0, stream>>>(sTb, bits);
    out256_kernel<<<dim3(16, 4, 4), 512, 131072, stream>>>(vB, sTb, P);
    reduce_kernel<<<dim3(DOc * LXc / 2048), 256, 0, stream>>>(P, out);
}